// Round 9
// baseline (317.177 us; speedup 1.0000x reference)
//
#include <hip/hip_runtime.h>
#include <hip/hip_bf16.h>

#define EMB 512
#define NSTK 32
#define NPNT 64
#define BSZ 32

typedef __attribute__((ext_vector_type(8))) short bf16x8;
typedef __attribute__((ext_vector_type(4))) float f32x4;
typedef __attribute__((ext_vector_type(4))) unsigned short us4;
typedef __attribute__((ext_vector_type(8))) unsigned short us8;

static __device__ __forceinline__ unsigned short bf16bits(float x) {
    __hip_bfloat16 h = __float2bfloat16(x);
    return *reinterpret_cast<unsigned short*>(&h);
}

// ---------------------------------------------------------------------------
// Kernel A: split Wk and Wg (fp32, 512x512 each) into bf16 hi + lo parts.
// ---------------------------------------------------------------------------
__global__ void cvt_weights(const float* __restrict__ wk,
                            const float* __restrict__ wg,
                            __hip_bfloat16* __restrict__ wkh,
                            __hip_bfloat16* __restrict__ wkl,
                            __hip_bfloat16* __restrict__ wgh,
                            __hip_bfloat16* __restrict__ wgl) {
    int idx = blockIdx.x * blockDim.x + threadIdx.x;   // 0..131071, 4 elems each
    const float* src;
    __hip_bfloat16 *dh, *dl;
    int k;
    if (idx < 65536) { src = wk; dh = wkh; dl = wkl; k = idx; }
    else             { src = wg; dh = wgh; dl = wgl; k = idx - 65536; }
    f32x4 v = *reinterpret_cast<const f32x4*>(src + (size_t)k * 4);
    us4 oh, ol;
#pragma unroll
    for (int e = 0; e < 4; ++e) {
        __hip_bfloat16 h = __float2bfloat16(v[e]);
        float hf = __bfloat162float(h);
        oh[e] = *reinterpret_cast<unsigned short*>(&h);
        ol[e] = bf16bits(v[e] - hf);
    }
    *reinterpret_cast<us4*>(dh + (size_t)k * 4) = oh;
    *reinterpret_cast<us4*>(dl + (size_t)k * 4) = ol;
}

// ---------------------------------------------------------------------------
// Kernel B: sp_q / sp_v — fp32 GEMM: out[m][o] = lrelu(sc[o]*dot(W[o,:],S[:,m])+bi[o])
// ---------------------------------------------------------------------------
__global__ __launch_bounds__(256)
void qv_gemm(const float* __restrict__ sparse,
             const float* __restrict__ Wq, const float* __restrict__ sq, const float* __restrict__ bq,
             const float* __restrict__ Wv, const float* __restrict__ sv, const float* __restrict__ bv,
             float* __restrict__ outq, float* __restrict__ outv) {
    const float* W  = (blockIdx.z == 0) ? Wq : Wv;
    const float* sc = (blockIdx.z == 0) ? sq : sv;
    const float* bi = (blockIdx.z == 0) ? bq : bv;
    float* orow     = (blockIdx.z == 0) ? outq : outv;

    __shared__ float Wt[64][33];
    __shared__ float St[32][65];

    const int m0 = blockIdx.x * 64;
    const int o0 = blockIdx.y * 64;
    const int t  = threadIdx.x;
    const int ty = t >> 4, tx = t & 15;

    float acc[4][4] = {};

    for (int k0 = 0; k0 < 512; k0 += 32) {
        {
            int ol = t >> 2, kl = (t & 3) * 8;
            const float* p = W + (size_t)(o0 + ol) * 512 + k0 + kl;
            f32x4 v0 = *reinterpret_cast<const f32x4*>(p);
            f32x4 v1 = *reinterpret_cast<const f32x4*>(p + 4);
#pragma unroll
            for (int e = 0; e < 4; ++e) { Wt[ol][kl + e] = v0[e]; Wt[ol][kl + 4 + e] = v1[e]; }
        }
        {
            int kl = t >> 3, ml = (t & 7) * 8;
            int mm = m0 + ml;
            int bb = mm >> 5, iidx = mm & 31;
            const float* p = sparse + (size_t)bb * 16384 + (size_t)(k0 + kl) * 32 + iidx;
            f32x4 v0 = *reinterpret_cast<const f32x4*>(p);
            f32x4 v1 = *reinterpret_cast<const f32x4*>(p + 4);
#pragma unroll
            for (int e = 0; e < 4; ++e) { St[kl][ml + e] = v0[e]; St[kl][ml + 4 + e] = v1[e]; }
        }
        __syncthreads();
#pragma unroll
        for (int kk = 0; kk < 32; ++kk) {
            float av[4], bvv[4];
#pragma unroll
            for (int e = 0; e < 4; ++e) av[e]  = Wt[ty * 4 + e][kk];
#pragma unroll
            for (int e = 0; e < 4; ++e) bvv[e] = St[kk][tx * 4 + e];
#pragma unroll
            for (int a = 0; a < 4; ++a)
#pragma unroll
                for (int bb2 = 0; bb2 < 4; ++bb2) acc[a][bb2] += av[a] * bvv[bb2];
        }
        __syncthreads();
    }
#pragma unroll
    for (int ae = 0; ae < 4; ++ae) {
        int o = o0 + ty * 4 + ae;
        float s = sc[o], bb2 = bi[o];
#pragma unroll
        for (int be = 0; be < 4; ++be) {
            int mm = m0 + tx * 4 + be;
            float h = acc[ae][be] * s + bb2;
            h = (h >= 0.f) ? h : 0.2f * h;
            orow[(size_t)mm * 512 + o] = h;
        }
    }
}

// ---------------------------------------------------------------------------
// Kernel C: fused main. One WG (16 waves, 1024 thr) per (b,i).
// Wave w owns o-slice [w*32, w*32+32)  (fm in {0,1}).
// 2-term compensated GEMMs: A*B ~= Ah*Bh + Al*Bh.
// Manual 2-deep double-buffer with asm memory-fences so the compiler CANNOT
// sink the ks+1 loads below the ks MFMA block (R8's VGPR=60 showed it did).
// ---------------------------------------------------------------------------

// load 4 B-frags for k-step kk from XH
#define LOADB(dst, kk)                                                          \
    {                                                                           \
        _Pragma("unroll")                                                       \
        for (int fn = 0; fn < 4; ++fn)                                          \
            dst[fn] = *reinterpret_cast<const bf16x8*>(                         \
                &XH[fn * 16 + l15][(kk) * 32 + lk * 8]);                        \
    }

// load 4 A-frags (hi/lo for fm=0,1) for k-step kk
#define LOADA(dst, hi, lo, kk)                                                  \
    {                                                                           \
        dst[0] = *reinterpret_cast<const bf16x8*>((hi) + arow + (kk) * 32 + lk * 8);            \
        dst[1] = *reinterpret_cast<const bf16x8*>((lo) + arow + (kk) * 32 + lk * 8);            \
        dst[2] = *reinterpret_cast<const bf16x8*>((hi) + arow + 16 * 512 + (kk) * 32 + lk * 8); \
        dst[3] = *reinterpret_cast<const bf16x8*>((lo) + arow + 16 * 512 + (kk) * 32 + lk * 8); \
    }

#define MFMAB(A, B)                                                             \
    {                                                                           \
        _Pragma("unroll")                                                       \
        for (int fm = 0; fm < 2; ++fm)                                          \
            _Pragma("unroll")                                                   \
            for (int fn = 0; fn < 4; ++fn) {                                    \
                acc[fm][fn] = __builtin_amdgcn_mfma_f32_16x16x32_bf16(          \
                    A[2 * fm], B[fn], acc[fm][fn], 0, 0, 0);                    \
                acc[fm][fn] = __builtin_amdgcn_mfma_f32_16x16x32_bf16(          \
                    A[2 * fm + 1], B[fn], acc[fm][fn], 0, 0, 0);                \
            }                                                                   \
    }

#define FENCE asm volatile("" ::: "memory")

__global__ __launch_bounds__(1024, 4)
void fused_attn(const float* __restrict__ dense,
                const __hip_bfloat16* __restrict__ wkh,
                const __hip_bfloat16* __restrict__ wkl,
                const __hip_bfloat16* __restrict__ wgh,
                const __hip_bfloat16* __restrict__ wgl,
                const float* __restrict__ wsq,
                const float* __restrict__ wsv,
                const float* __restrict__ sk, const float* __restrict__ bk,
                const float* __restrict__ sg, const float* __restrict__ bg,
                float* __restrict__ out) {
    __shared__ __align__(16) __hip_bfloat16 XH[64][520];   // 66.5 KB, X -> Dh
    __shared__ __align__(16) float qrow[512];
    __shared__ __align__(16) float vrow[512];
    __shared__ float wredA[16][64];
    __shared__ float wredB[16][64];

    const int m   = blockIdx.x;        // 0..1023
    const int b   = m >> 5, ii = m & 31;
    const int tid = threadIdx.x;       // 0..1023
    const int w   = tid >> 6;          // wave 0..15
    const int l   = tid & 63;
    const int l15 = l & 15;
    const int lk  = l >> 4;            // 0..3

    if (tid < 512) qrow[tid] = wsq[(size_t)m * 512 + tid];
    else           vrow[tid - 512] = wsv[(size_t)m * 512 + (tid - 512)];

    {   // stage X: thread owns j-row l, c-block [w*32, +32); b128 LDS writes
        const float* src = dense + (size_t)b * 512 * 2048 + (size_t)ii * 64 + l;
#pragma unroll
        for (int e8 = 0; e8 < 4; ++e8) {
            const int c0 = w * 32 + e8 * 8;
            us8 pk;
#pragma unroll
            for (int e = 0; e < 8; ++e)
                pk[e] = bf16bits(src[(size_t)(c0 + e) * 2048]);
            *reinterpret_cast<us8*>(&XH[l][c0]) = pk;
        }
    }
    __syncthreads();

    f32x4 acc[2][4];
#pragma unroll
    for (int fm = 0; fm < 2; ++fm)
#pragma unroll
        for (int fn = 0; fn < 4; ++fn) acc[fm][fn] = (f32x4){0.f, 0.f, 0.f, 0.f};

    const size_t arow = (size_t)(w * 32 + l15) * 512;   // wave's A row base (elem)

    // ---- GEMM1: dn_k[o,j] = sum_c Wk[o,c] * X[c,j]   (Ah+Al compensated)
    {
        bf16x8 a0[4], b0[4], a1[4], b1[4];
        LOADB(b0, 0);
        LOADA(a0, wkh, wkl, 0);
#pragma unroll
        for (int ks2 = 0; ks2 < 8; ++ks2) {
            LOADB(b1, 2 * ks2 + 1);
            LOADA(a1, wkh, wkl, 2 * ks2 + 1);
            FENCE;                 // loads above may NOT sink below
            MFMAB(a0, b0);
            if (ks2 < 7) {         // WAR on a0/b0 keeps these after MFMAB(a0,b0)
                LOADB(b0, 2 * ks2 + 2);
                LOADA(a0, wkh, wkl, 2 * ks2 + 2);
            }
            FENCE;
            MFMAB(a1, b1);
        }
    }

    // GEMM2 A-prologue (weights independent of Dh): issue before the barrier
    bf16x8 a2[4];
    LOADA(a2, wgh, wgl, 0);
    __syncthreads();   // all waves done reading XH

    // ---- epilogue1: d = q - lrelu(acc*sk+bk), bf16, write Dh over XH
#pragma unroll
    for (int fm = 0; fm < 2; ++fm) {
        const int o0 = w * 32 + fm * 16 + lk * 4;
        f32x4 skv = *reinterpret_cast<const f32x4*>(sk + o0);
        f32x4 bkv = *reinterpret_cast<const f32x4*>(bk + o0);
        f32x4 qv4 = *reinterpret_cast<const f32x4*>(&qrow[o0]);
#pragma unroll
        for (int fn = 0; fn < 4; ++fn) {
            const int j = fn * 16 + l15;
            us4 pkh;
#pragma unroll
            for (int r = 0; r < 4; ++r) {
                float h = acc[fm][fn][r] * skv[r] + bkv[r];
                h = (h >= 0.f) ? h : 0.2f * h;
                pkh[r] = bf16bits(qv4[r] - h);
            }
            *reinterpret_cast<us4*>(&XH[j][o0]) = pkh;   // 8B store, o0 % 4 == 0
        }
    }
    __syncthreads();

    // ---- GEMM2: g[oo,j] = sum_o Wg[oo,o] * d[o,j]   (Ah+Al compensated)
#pragma unroll
    for (int fm = 0; fm < 2; ++fm)
#pragma unroll
        for (int fn = 0; fn < 4; ++fn) acc[fm][fn] = (f32x4){0.f, 0.f, 0.f, 0.f};

    {
        bf16x8 a0[4], b0[4], a1[4], b1[4];
#pragma unroll
        for (int e = 0; e < 4; ++e) a0[e] = a2[e];
        LOADB(b0, 0);
#pragma unroll
        for (int ks2 = 0; ks2 < 8; ++ks2) {
            LOADB(b1, 2 * ks2 + 1);
            LOADA(a1, wgh, wgl, 2 * ks2 + 1);
            FENCE;
            MFMAB(a0, b0);
            if (ks2 < 7) {
                LOADB(b0, 2 * ks2 + 2);
                LOADA(a0, wgh, wgl, 2 * ks2 + 2);
            }
            FENCE;
            MFMAB(a1, b1);
        }
    }

    // ---- epilogue2 in place: g = lrelu(acc*sg+bg)
#pragma unroll
    for (int fm = 0; fm < 2; ++fm) {
        const int o0 = w * 32 + fm * 16 + lk * 4;
        f32x4 sgv = *reinterpret_cast<const f32x4*>(sg + o0);
        f32x4 bgv = *reinterpret_cast<const f32x4*>(bg + o0);
#pragma unroll
        for (int fn = 0; fn < 4; ++fn)
#pragma unroll
            for (int r = 0; r < 4; ++r) {
                float h = acc[fm][fn][r] * sgv[r] + bgv[r];
                acc[fm][fn][r] = (h >= 0.f) ? h : 0.2f * h;
            }
    }

    // ---- softmax over the 512 channels, per j column
    float pm[4];
#pragma unroll
    for (int fn = 0; fn < 4; ++fn) {
        float mx = -1e30f;
#pragma unroll
        for (int fm = 0; fm < 2; ++fm)
#pragma unroll
            for (int r = 0; r < 4; ++r) mx = fmaxf(mx, acc[fm][fn][r]);
        mx = fmaxf(mx, __shfl_xor(mx, 16, 64));
        mx = fmaxf(mx, __shfl_xor(mx, 32, 64));
        pm[fn] = mx;
    }
    if (l < 16) {
#pragma unroll
        for (int fn = 0; fn < 4; ++fn) wredA[w][fn * 16 + l] = pm[fn];
    }
    __syncthreads();

    float jmax[4];
#pragma unroll
    for (int fn = 0; fn < 4; ++fn) {
        float mx = wredA[0][fn * 16 + l15];
#pragma unroll
        for (int ww = 1; ww < 16; ++ww) mx = fmaxf(mx, wredA[ww][fn * 16 + l15]);
        jmax[fn] = mx;
    }

    float ps[4] = {0.f, 0.f, 0.f, 0.f};
#pragma unroll
    for (int fm = 0; fm < 2; ++fm)
#pragma unroll
        for (int fn = 0; fn < 4; ++fn)
#pragma unroll
            for (int r = 0; r < 4; ++r) {
                float e = __expf(acc[fm][fn][r] - jmax[fn]);
                acc[fm][fn][r] = e;
                ps[fn] += e;
            }
#pragma unroll
    for (int fn = 0; fn < 4; ++fn) {
        ps[fn] += __shfl_xor(ps[fn], 16, 64);
        ps[fn] += __shfl_xor(ps[fn], 32, 64);
    }
    if (l < 16) {
#pragma unroll
        for (int fn = 0; fn < 4; ++fn) wredB[w][fn * 16 + l] = ps[fn];
    }
    __syncthreads();

    float rinv[4];
#pragma unroll
    for (int fn = 0; fn < 4; ++fn) {
        float s = 0.f;
#pragma unroll
        for (int ww = 0; ww < 16; ++ww) s += wredB[ww][fn * 16 + l15];
        rinv[fn] = 1.f / s;
    }

    // ---- out[b,oo,i] = sp_v[oo] * sum_j coef[oo,j]   (FP32 store)
#pragma unroll
    for (int fm = 0; fm < 2; ++fm) {
#pragma unroll
        for (int r = 0; r < 4; ++r) {
            float tsum = 0.f;
#pragma unroll
            for (int fn = 0; fn < 4; ++fn) tsum += acc[fm][fn][r] * rinv[fn];
            tsum += __shfl_xor(tsum, 1, 64);
            tsum += __shfl_xor(tsum, 2, 64);
            tsum += __shfl_xor(tsum, 4, 64);
            tsum += __shfl_xor(tsum, 8, 64);
            if (l15 == 0) {
                int oo = w * 32 + fm * 16 + lk * 4 + r;
                out[((size_t)b * 512 + oo) * 32 + ii] = vrow[oo] * tsum;
            }
        }
    }
}

// ---------------------------------------------------------------------------
extern "C" void kernel_launch(void* const* d_in, const int* in_sizes, int n_in,
                              void* d_out, int out_size, void* d_ws, size_t ws_size,
                              hipStream_t stream) {
    const float* sparse = (const float*)d_in[0];
    const float* dense  = (const float*)d_in[1];
    const float* Wq = (const float*)d_in[2];
    const float* sq = (const float*)d_in[3];
    const float* bq = (const float*)d_in[4];
    const float* Wk = (const float*)d_in[5];
    const float* sk = (const float*)d_in[6];
    const float* bk = (const float*)d_in[7];
    const float* Wv = (const float*)d_in[8];
    const float* sv = (const float*)d_in[9];
    const float* bv = (const float*)d_in[10];
    const float* Wg = (const float*)d_in[11];
    const float* sg = (const float*)d_in[12];
    const float* bg = (const float*)d_in[13];
    float* out = (float*)d_out;

    // workspace: [sp_q f32 2MB][sp_v f32 2MB][Wk hi/lo bf16 1MB][Wg hi/lo bf16 1MB]
    float* wsq = (float*)d_ws;
    float* wsv = wsq + 1024 * 512;
    __hip_bfloat16* wkh = (__hip_bfloat16*)(wsv + 1024 * 512);
    __hip_bfloat16* wkl = wkh + 512 * 512;
    __hip_bfloat16* wgh = wkl + 512 * 512;
    __hip_bfloat16* wgl = wgh + 512 * 512;

    cvt_weights<<<512, 256, 0, stream>>>(Wk, Wg, wkh, wkl, wgh, wgl);
    qv_gemm<<<dim3(16, 8, 2), 256, 0, stream>>>(sparse, Wq, sq, bq, Wv, sv, bv, wsq, wsv);
    fused_attn<<<1024, 1024, 0, stream>>>(dense, wkh, wkl, wgh, wgl, wsq, wsv, sk, bk, sg, bg, out);
}

// Round 10
// 193.727 us; speedup vs baseline: 1.6372x; 1.6372x over previous
//
#include <hip/hip_runtime.h>
#include <hip/hip_bf16.h>

#define EMB 512
#define NSTK 32
#define NPNT 64
#define BSZ 32

typedef __attribute__((ext_vector_type(8))) _Float16 f16x8;
typedef __attribute__((ext_vector_type(4))) float f32x4;
typedef __attribute__((ext_vector_type(4))) unsigned short us4;
typedef __attribute__((ext_vector_type(8))) unsigned short us8;

static __device__ __forceinline__ unsigned short f16bits(float x) {
    _Float16 h = (_Float16)x;
    return *reinterpret_cast<unsigned short*>(&h);
}

// async global->LDS DMA: dest = wave-uniform lds base + lane*16 (m104 semantics)
#define GLL(gsrc, ldst)                                                         \
    __builtin_amdgcn_global_load_lds(                                           \
        (const __attribute__((address_space(1))) void*)(gsrc),                  \
        (__attribute__((address_space(3))) void*)(ldst), 16, 0, 0)

// ---------------------------------------------------------------------------
// Kernel A: convert Wk and Wg (fp32 512x512) to f16.
// ---------------------------------------------------------------------------
__global__ void cvt_weights(const float* __restrict__ wk,
                            const float* __restrict__ wg,
                            _Float16* __restrict__ wkf,
                            _Float16* __restrict__ wgf) {
    int idx = blockIdx.x * blockDim.x + threadIdx.x;   // 0..131071, 4 elems each
    const float* src;
    _Float16* dst;
    int k;
    if (idx < 65536) { src = wk; dst = wkf; k = idx; }
    else             { src = wg; dst = wgf; k = idx - 65536; }
    f32x4 v = *reinterpret_cast<const f32x4*>(src + (size_t)k * 4);
    us4 o;
#pragma unroll
    for (int e = 0; e < 4; ++e) o[e] = f16bits(v[e]);
    *reinterpret_cast<us4*>(dst + (size_t)k * 4) = o;
}

// ---------------------------------------------------------------------------
// Kernel B: sp_q / sp_v — fp32 GEMM (unchanged).
// ---------------------------------------------------------------------------
__global__ __launch_bounds__(256)
void qv_gemm(const float* __restrict__ sparse,
             const float* __restrict__ Wq, const float* __restrict__ sq, const float* __restrict__ bq,
             const float* __restrict__ Wv, const float* __restrict__ sv, const float* __restrict__ bv,
             float* __restrict__ outq, float* __restrict__ outv) {
    const float* W  = (blockIdx.z == 0) ? Wq : Wv;
    const float* sc = (blockIdx.z == 0) ? sq : sv;
    const float* bi = (blockIdx.z == 0) ? bq : bv;
    float* orow     = (blockIdx.z == 0) ? outq : outv;

    __shared__ float Wt[64][33];
    __shared__ float St[32][65];

    const int m0 = blockIdx.x * 64;
    const int o0 = blockIdx.y * 64;
    const int t  = threadIdx.x;
    const int ty = t >> 4, tx = t & 15;

    float acc[4][4] = {};

    for (int k0 = 0; k0 < 512; k0 += 32) {
        {
            int ol = t >> 2, kl = (t & 3) * 8;
            const float* p = W + (size_t)(o0 + ol) * 512 + k0 + kl;
            f32x4 v0 = *reinterpret_cast<const f32x4*>(p);
            f32x4 v1 = *reinterpret_cast<const f32x4*>(p + 4);
#pragma unroll
            for (int e = 0; e < 4; ++e) { Wt[ol][kl + e] = v0[e]; Wt[ol][kl + 4 + e] = v1[e]; }
        }
        {
            int kl = t >> 3, ml = (t & 7) * 8;
            int mm = m0 + ml;
            int bb = mm >> 5, iidx = mm & 31;
            const float* p = sparse + (size_t)bb * 16384 + (size_t)(k0 + kl) * 32 + iidx;
            f32x4 v0 = *reinterpret_cast<const f32x4*>(p);
            f32x4 v1 = *reinterpret_cast<const f32x4*>(p + 4);
#pragma unroll
            for (int e = 0; e < 4; ++e) { St[kl][ml + e] = v0[e]; St[kl][ml + 4 + e] = v1[e]; }
        }
        __syncthreads();
#pragma unroll
        for (int kk = 0; kk < 32; ++kk) {
            float av[4], bvv[4];
#pragma unroll
            for (int e = 0; e < 4; ++e) av[e]  = Wt[ty * 4 + e][kk];
#pragma unroll
            for (int e = 0; e < 4; ++e) bvv[e] = St[kk][tx * 4 + e];
#pragma unroll
            for (int a = 0; a < 4; ++a)
#pragma unroll
                for (int bb2 = 0; bb2 < 4; ++bb2) acc[a][bb2] += av[a] * bvv[bb2];
        }
        __syncthreads();
    }
#pragma unroll
    for (int ae = 0; ae < 4; ++ae) {
        int o = o0 + ty * 4 + ae;
        float s = sc[o], bb2 = bi[o];
#pragma unroll
        for (int be = 0; be < 4; ++be) {
            int mm = m0 + tx * 4 + be;
            float h = acc[ae][be] * s + bb2;
            h = (h >= 0.f) ? h : 0.2f * h;
            orow[(size_t)mm * 512 + o] = h;
        }
    }
}

// ---------------------------------------------------------------------------
// Kernel C: fused main. One WG (16 waves, 1024 thr) per (b,i).
// f16 single-term MFMA GEMMs. Weight K-panels (512 o x 32 k f16 = 32 KB)
// double-buffered in LDS via global_load_lds (async DMA, no VGPR round-trip),
// one __syncthreads per ks (compiler emits the vmcnt drain at the barrier).
// Wave w owns o-rows [w*32, w*32+32)  (fm in {0,1}).
// ---------------------------------------------------------------------------
__global__ __launch_bounds__(1024, 4)
void fused_attn(const float* __restrict__ dense,
                const _Float16* __restrict__ wkf,
                const _Float16* __restrict__ wgf,
                const float* __restrict__ wsq,
                const float* __restrict__ wsv,
                const float* __restrict__ sk, const float* __restrict__ bk,
                const float* __restrict__ sg, const float* __restrict__ bg,
                float* __restrict__ out) {
    __shared__ __align__(16) _Float16 XH[64][520];     // 66.5 KB, X -> D (f16)
    __shared__ __align__(16) _Float16 WP[2][512 * 32]; // 2 x 32 KB weight panels
    __shared__ __align__(16) float qrow[512];
    __shared__ __align__(16) float vrow[512];
    __shared__ float wredA[16][64];
    __shared__ float wredB[16][64];

    const int m   = blockIdx.x;        // 0..1023
    const int b   = m >> 5, ii = m & 31;
    const int tid = threadIdx.x;       // 0..1023
    const int w   = tid >> 6;          // wave 0..15
    const int l   = tid & 63;
    const int l15 = l & 15;
    const int lk  = l >> 4;            // 0..3

    // ---- prologue: start DMA of Wk panel 0 into WP[0] (overlaps X staging)
    {
        const _Float16* wsp = wkf;     // panel ks=0
#pragma unroll
        for (int ih = 0; ih < 2; ++ih) {
            const int o = w * 32 + ih * 16 + (l >> 2);
            const int t = l & 3;
            const _Float16* gp = wsp + (size_t)o * 512 + t * 8;
            _Float16* lp = &WP[0][(w * 32 + ih * 16) * 32];   // wave-uniform
            GLL(gp, lp);
        }
    }

    if (tid < 512) qrow[tid] = wsq[(size_t)m * 512 + tid];
    else           vrow[tid - 512] = wsv[(size_t)m * 512 + (tid - 512)];

    {   // stage X (f16): thread owns j-row l, c-block [w*32, +32)
        const float* src = dense + (size_t)b * 512 * 2048 + (size_t)ii * 64 + l;
#pragma unroll
        for (int e8 = 0; e8 < 4; ++e8) {
            const int c0 = w * 32 + e8 * 8;
            us8 pk;
#pragma unroll
            for (int e = 0; e < 8; ++e)
                pk[e] = f16bits(src[(size_t)(c0 + e) * 2048]);
            *reinterpret_cast<us8*>(&XH[l][c0]) = pk;
        }
    }
    __syncthreads();   // drains the panel-0 DMA too

    f32x4 acc[2][4];
#pragma unroll
    for (int fm = 0; fm < 2; ++fm)
#pragma unroll
        for (int fn = 0; fn < 4; ++fn) acc[fm][fn] = (f32x4){0.f, 0.f, 0.f, 0.f};

    // ---- GEMM1: dn_k[o,j] = sum_c Wk[o,c] * X[c,j]
    for (int ks = 0; ks < 16; ++ks) {
        {   // prefetch next panel (last iter prefetches Wg panel 0)
            const _Float16* wsp = (ks < 15) ? (wkf + (size_t)(ks + 1) * 32)
                                            : wgf;
            const int pb = (ks + 1) & 1;
#pragma unroll
            for (int ih = 0; ih < 2; ++ih) {
                const int o = w * 32 + ih * 16 + (l >> 2);
                const int t = l & 3;
                const _Float16* gp = wsp + (size_t)o * 512 + t * 8;
                _Float16* lp = &WP[pb][(w * 32 + ih * 16) * 32];
                GLL(gp, lp);
            }
        }
        {   // compute from WP[ks&1]
            const _Float16* pbuf = WP[ks & 1];
            f16x8 af[2], bf[4];
#pragma unroll
            for (int fm = 0; fm < 2; ++fm)
                af[fm] = *reinterpret_cast<const f16x8*>(pbuf + (w * 32 + fm * 16 + l15) * 32 + lk * 8);
#pragma unroll
            for (int fn = 0; fn < 4; ++fn)
                bf[fn] = *reinterpret_cast<const f16x8*>(&XH[fn * 16 + l15][ks * 32 + lk * 8]);
#pragma unroll
            for (int fm = 0; fm < 2; ++fm)
#pragma unroll
                for (int fn = 0; fn < 4; ++fn)
                    acc[fm][fn] = __builtin_amdgcn_mfma_f32_16x16x32_f16(af[fm], bf[fn], acc[fm][fn], 0, 0, 0);
        }
        __syncthreads();   // vmcnt+lgkm drain: next panel ready, buffers safe
    }

    // ---- epilogue1: d = q - lrelu(acc*sk+bk), f16, write D over XH
#pragma unroll
    for (int fm = 0; fm < 2; ++fm) {
        const int o0 = w * 32 + fm * 16 + lk * 4;
        f32x4 skv = *reinterpret_cast<const f32x4*>(sk + o0);
        f32x4 bkv = *reinterpret_cast<const f32x4*>(bk + o0);
        f32x4 qv4 = *reinterpret_cast<const f32x4*>(&qrow[o0]);
#pragma unroll
        for (int fn = 0; fn < 4; ++fn) {
            const int j = fn * 16 + l15;
            us4 pkh;
#pragma unroll
            for (int r = 0; r < 4; ++r) {
                float h = acc[fm][fn][r] * skv[r] + bkv[r];
                h = (h >= 0.f) ? h : 0.2f * h;
                pkh[r] = f16bits(qv4[r] - h);
            }
            *reinterpret_cast<us4*>(&XH[j][o0]) = pkh;   // 8B store, o0 % 4 == 0
        }
    }
    __syncthreads();

    // ---- GEMM2: g[oo,j] = sum_o Wg[oo,o] * d[o,j]
#pragma unroll
    for (int fm = 0; fm < 2; ++fm)
#pragma unroll
        for (int fn = 0; fn < 4; ++fn) acc[fm][fn] = (f32x4){0.f, 0.f, 0.f, 0.f};

    for (int ks = 0; ks < 16; ++ks) {
        if (ks < 15) {   // prefetch next Wg panel
            const _Float16* wsp = wgf + (size_t)(ks + 1) * 32;
            const int pb = (ks + 1) & 1;
#pragma unroll
            for (int ih = 0; ih < 2; ++ih) {
                const int o = w * 32 + ih * 16 + (l >> 2);
                const int t = l & 3;
                const _Float16* gp = wsp + (size_t)o * 512 + t * 8;
                _Float16* lp = &WP[pb][(w * 32 + ih * 16) * 32];
                GLL(gp, lp);
            }
        }
        {
            const _Float16* pbuf = WP[ks & 1];
            f16x8 af[2], bf[4];
#pragma unroll
            for (int fm = 0; fm < 2; ++fm)
                af[fm] = *reinterpret_cast<const f16x8*>(pbuf + (w * 32 + fm * 16 + l15) * 32 + lk * 8);
#pragma unroll
            for (int fn = 0; fn < 4; ++fn)
                bf[fn] = *reinterpret_cast<const f16x8*>(&XH[fn * 16 + l15][ks * 32 + lk * 8]);
#pragma unroll
            for (int fm = 0; fm < 2; ++fm)
#pragma unroll
                for (int fn = 0; fn < 4; ++fn)
                    acc[fm][fn] = __builtin_amdgcn_mfma_f32_16x16x32_f16(af[fm], bf[fn], acc[fm][fn], 0, 0, 0);
        }
        __syncthreads();
    }

    // ---- epilogue2 in place: g = lrelu(acc*sg+bg)
#pragma unroll
    for (int fm = 0; fm < 2; ++fm) {
        const int o0 = w * 32 + fm * 16 + lk * 4;
        f32x4 sgv = *reinterpret_cast<const f32x4*>(sg + o0);
        f32x4 bgv = *reinterpret_cast<const f32x4*>(bg + o0);
#pragma unroll
        for (int fn = 0; fn < 4; ++fn)
#pragma unroll
            for (int r = 0; r < 4; ++r) {
                float h = acc[fm][fn][r] * sgv[r] + bgv[r];
                acc[fm][fn][r] = (h >= 0.f) ? h : 0.2f * h;
            }
    }

    // ---- softmax over the 512 channels, per j column
    float pm[4];
#pragma unroll
    for (int fn = 0; fn < 4; ++fn) {
        float mx = -1e30f;
#pragma unroll
        for (int fm = 0; fm < 2; ++fm)
#pragma unroll
            for (int r = 0; r < 4; ++r) mx = fmaxf(mx, acc[fm][fn][r]);
        mx = fmaxf(mx, __shfl_xor(mx, 16, 64));
        mx = fmaxf(mx, __shfl_xor(mx, 32, 64));
        pm[fn] = mx;
    }
    if (l < 16) {
#pragma unroll
        for (int fn = 0; fn < 4; ++fn) wredA[w][fn * 16 + l] = pm[fn];
    }
    __syncthreads();

    float jmax[4];
#pragma unroll
    for (int fn = 0; fn < 4; ++fn) {
        float mx = wredA[0][fn * 16 + l15];
#pragma unroll
        for (int ww = 1; ww < 16; ++ww) mx = fmaxf(mx, wredA[ww][fn * 16 + l15]);
        jmax[fn] = mx;
    }

    float ps[4] = {0.f, 0.f, 0.f, 0.f};
#pragma unroll
    for (int fm = 0; fm < 2; ++fm)
#pragma unroll
        for (int fn = 0; fn < 4; ++fn)
#pragma unroll
            for (int r = 0; r < 4; ++r) {
                float e = __expf(acc[fm][fn][r] - jmax[fn]);
                acc[fm][fn][r] = e;
                ps[fn] += e;
            }
#pragma unroll
    for (int fn = 0; fn < 4; ++fn) {
        ps[fn] += __shfl_xor(ps[fn], 16, 64);
        ps[fn] += __shfl_xor(ps[fn], 32, 64);
    }
    if (l < 16) {
#pragma unroll
        for (int fn = 0; fn < 4; ++fn) wredB[w][fn * 16 + l] = ps[fn];
    }
    __syncthreads();

    float rinv[4];
#pragma unroll
    for (int fn = 0; fn < 4; ++fn) {
        float s = 0.f;
#pragma unroll
        for (int ww = 0; ww < 16; ++ww) s += wredB[ww][fn * 16 + l15];
        rinv[fn] = 1.f / s;
    }

    // ---- out[b,oo,i] = sp_v[oo] * sum_j coef[oo,j]   (FP32 store)
#pragma unroll
    for (int fm = 0; fm < 2; ++fm) {
#pragma unroll
        for (int r = 0; r < 4; ++r) {
            float tsum = 0.f;
#pragma unroll
            for (int fn = 0; fn < 4; ++fn) tsum += acc[fm][fn][r] * rinv[fn];
            tsum += __shfl_xor(tsum, 1, 64);
            tsum += __shfl_xor(tsum, 2, 64);
            tsum += __shfl_xor(tsum, 4, 64);
            tsum += __shfl_xor(tsum, 8, 64);
            if (l15 == 0) {
                int oo = w * 32 + fm * 16 + lk * 4 + r;
                out[((size_t)b * 512 + oo) * 32 + ii] = vrow[oo] * tsum;
            }
        }
    }
}

// ---------------------------------------------------------------------------
extern "C" void kernel_launch(void* const* d_in, const int* in_sizes, int n_in,
                              void* d_out, int out_size, void* d_ws, size_t ws_size,
                              hipStream_t stream) {
    const float* sparse = (const float*)d_in[0];
    const float* dense  = (const float*)d_in[1];
    const float* Wq = (const float*)d_in[2];
    const float* sq = (const float*)d_in[3];
    const float* bq = (const float*)d_in[4];
    const float* Wk = (const float*)d_in[5];
    const float* sk = (const float*)d_in[6];
    const float* bk = (const float*)d_in[7];
    const float* Wv = (const float*)d_in[8];
    const float* sv = (const float*)d_in[9];
    const float* bv = (const float*)d_in[10];
    const float* Wg = (const float*)d_in[11];
    const float* sg = (const float*)d_in[12];
    const float* bg = (const float*)d_in[13];
    float* out = (float*)d_out;

    // workspace: [sp_q f32 2MB][sp_v f32 2MB][Wk f16 512KB][Wg f16 512KB]
    float* wsq = (float*)d_ws;
    float* wsv = wsq + 1024 * 512;
    _Float16* wkf = (_Float16*)(wsv + 1024 * 512);
    _Float16* wgf = wkf + 512 * 512;

    cvt_weights<<<512, 256, 0, stream>>>(Wk, Wg, wkf, wgf);
    qv_gemm<<<dim3(16, 8, 2), 256, 0, stream>>>(sparse, Wq, sq, bq, Wv, sv, bv, wsq, wsv);
    fused_attn<<<1024, 1024, 0, stream>>>(dense, wkf, wgf, wsq, wsv, sk, bk, sg, bg, out);
}